// Round 11
// baseline (46.750 us; speedup 1.0000x reference)
//
#include <hip/hip_runtime.h>
#include <math.h>

#define NK 32           // knots
#define NP 36           // NK + 4 (system size)
#define PX 8            // pixels per thread in apply

// hardware v_sqrt_f32 (~1 ulp) — __sqrtf collides with glibc math.h macros
__device__ __forceinline__ float hw_sqrtf(float x) {
    return __builtin_amdgcn_sqrtf(x);
}

// ---------------------------------------------------------------------------
// Full-wave (64-lane) max of an unsigned via DPP; result is wave-uniform
// (returned through readlane 63 -> SGPR). All-VALU, no LDS latency.
// ---------------------------------------------------------------------------
__device__ __forceinline__ unsigned wave_max64(unsigned x) {
    unsigned t;
    t = (unsigned)__builtin_amdgcn_update_dpp(0, (int)x, 0x111, 0xF, 0xF, true); x = x > t ? x : t; // row_shr:1
    t = (unsigned)__builtin_amdgcn_update_dpp(0, (int)x, 0x112, 0xF, 0xF, true); x = x > t ? x : t; // row_shr:2
    t = (unsigned)__builtin_amdgcn_update_dpp(0, (int)x, 0x114, 0xF, 0xF, true); x = x > t ? x : t; // row_shr:4
    t = (unsigned)__builtin_amdgcn_update_dpp(0, (int)x, 0x118, 0xF, 0xF, true); x = x > t ? x : t; // row_shr:8
    t = (unsigned)__builtin_amdgcn_update_dpp(0, (int)x, 0x142, 0xA, 0xF, true); x = x > t ? x : t; // row_bcast:15
    t = (unsigned)__builtin_amdgcn_update_dpp(0, (int)x, 0x143, 0xC, 0xF, true); x = x > t ? x : t; // row_bcast:31
    return (unsigned)__builtin_amdgcn_readlane((int)x, 63);
}

// broadcast float from lane sl (wave-uniform SGPR) — pure bit ops, no alloca
__device__ __forceinline__ float bcastf(float v, int sl) {
    return __int_as_float(__builtin_amdgcn_readlane(__float_as_int(v), sl));
}

// ---------------------------------------------------------------------------
// FUSED kernel. Phase 1: waves 0..2 each solve one (batch,channel) 36x37
// system — R10's lane-parallel pivoted Gauss-Jordan on 37 NAMED fp32 scalars
// (proven correct, absmax 0.125) with a 2-op column update:
//   minv = (isp ? pv-1 : rr_K) * (1/pv);  rr_c -= minv * readlane(rr_c, prid)
// (for the pivot lane this scales its row by 1/pv; for others it eliminates).
// Wave 3 stages the knot float4 table. W goes to LDS; one barrier; Phase 2 is
// the unchanged PX=8 apply. Every block redundantly solves its batch's
// systems on otherwise-idle SIMDs — no tiny 24-block dispatch, no d_ws.
// ---------------------------------------------------------------------------
__global__ __launch_bounds__(256, 1) void tps_fused(const float* __restrict__ raw,
                                                    const float* __restrict__ params,
                                                    float* __restrict__ out,
                                                    int HW) {
    __shared__ float  sxs[NK * 3];
    __shared__ float4 sX[NK];
    __shared__ float4 sW4[NP];

    int b   = blockIdx.y;
    int tid = threadIdx.x;
    const float* pp = params + (size_t)b * (6 * NK + 3);

    // stage all 96 knot floats (ALL threads; bug R8/R9 was a short load here)
    if (tid < NK * 3) sxs[tid] = pp[tid];
    __syncthreads();

    int wid  = tid >> 6;
    int lane = tid & 63;

    if (wid < 3) {
        // ================= Phase 1: solve channel `wid` =================
        int ch = wid;
        float lam = pp[6 * NK + ch];

        int li = (lane < NK) ? lane : 0;
        float myx0 = sxs[li*3+0], myx1 = sxs[li*3+1], myx2 = sxs[li*3+2];

        float rr0,rr1,rr2,rr3,rr4,rr5,rr6,rr7,rr8,rr9,rr10,rr11,rr12,rr13,
              rr14,rr15,rr16,rr17,rr18,rr19,rr20,rr21,rr22,rr23,rr24,rr25,
              rr26,rr27,rr28,rr29,rr30,rr31,rr32,rr33,rr34,rr35,rr36;

        float bcomp = (lane == 33) ? 0.f : (lane == 34) ? 1.f : 2.f;
#define BUILDC(c) do {                                                        \
    float xc0 = sxs[(c)*3+0], xc1 = sxs[(c)*3+1], xc2 = sxs[(c)*3+2];         \
    float dx = myx0 - xc0, dy = myx1 - xc1, dz = myx2 - xc2;                  \
    float d  = hw_sqrtf(dx*dx + dy*dy + dz*dz);                               \
    float v;                                                                  \
    if (lane < NK)       v = (lane == (c)) ? lam : d;                         \
    else if (lane == 32) v = 1.0f;                                            \
    else if (lane < NP)  v = (bcomp==0.f)?xc0:(bcomp==1.f)?xc1:xc2;           \
    else                 v = 0.0f;                                            \
    rr##c = v;                                                                \
} while (0)
        BUILDC(0);  BUILDC(1);  BUILDC(2);  BUILDC(3);  BUILDC(4);  BUILDC(5);
        BUILDC(6);  BUILDC(7);  BUILDC(8);  BUILDC(9);  BUILDC(10); BUILDC(11);
        BUILDC(12); BUILDC(13); BUILDC(14); BUILDC(15); BUILDC(16); BUILDC(17);
        BUILDC(18); BUILDC(19); BUILDC(20); BUILDC(21); BUILDC(22); BUILDC(23);
        BUILDC(24); BUILDC(25); BUILDC(26); BUILDC(27); BUILDC(28); BUILDC(29);
        BUILDC(30); BUILDC(31);
#undef BUILDC
        bool top = (lane < NK);
        rr32 = top ? 1.0f : 0.0f;
        rr33 = top ? myx0 : 0.0f;
        rr34 = top ? myx1 : 0.0f;
        rr35 = top ? myx2 : 0.0f;
        rr36 = top ? pp[3*NK + li*3 + ch] : 0.0f;   // rhs = ys[lane][ch]

        unsigned used = (lane >= NP) ? 1u : 0u;
        int kown = -1;

#define COLU(c) if ((c) > KK) { rr##c -= minv * bcastf(rr##c, prid); }
#define ALLCOLS \
    COLU(1)  COLU(2)  COLU(3)  COLU(4)  COLU(5)  COLU(6)  COLU(7)  COLU(8)  \
    COLU(9)  COLU(10) COLU(11) COLU(12) COLU(13) COLU(14) COLU(15) COLU(16) \
    COLU(17) COLU(18) COLU(19) COLU(20) COLU(21) COLU(22) COLU(23) COLU(24) \
    COLU(25) COLU(26) COLU(27) COLU(28) COLU(29) COLU(30) COLU(31) COLU(32) \
    COLU(33) COLU(34) COLU(35) COLU(36)
#define STEP(Kv) do {                                                         \
    const int KK = (Kv);                                                      \
    unsigned pk_ = (__float_as_uint(fabsf(rr##Kv)) & 0xFFFFFFC0u)             \
                 | (unsigned)lane;                                            \
    pk_ = used ? 0u : pk_;                                                    \
    int prid  = (int)(wave_max64(pk_) & 63u);                                 \
    float pv  = bcastf(rr##Kv, prid);                                         \
    float inv = 1.0f / pv;                                                    \
    bool  isp = (lane == prid);                                               \
    float m   = isp ? (pv - 1.0f) : rr##Kv;                                   \
    float minv = m * inv;                                                     \
    if (isp) { used = 1u; kown = (Kv); }                                      \
    ALLCOLS                                                                   \
} while (0)

        STEP(0);  STEP(1);  STEP(2);  STEP(3);  STEP(4);  STEP(5);
        STEP(6);  STEP(7);  STEP(8);  STEP(9);  STEP(10); STEP(11);
        STEP(12); STEP(13); STEP(14); STEP(15); STEP(16); STEP(17);
        STEP(18); STEP(19); STEP(20); STEP(21); STEP(22); STEP(23);
        STEP(24); STEP(25); STEP(26); STEP(27); STEP(28); STEP(29);
        STEP(30); STEP(31); STEP(32); STEP(33); STEP(34); STEP(35);
#undef STEP
#undef ALLCOLS
#undef COLU

        if (kown >= 0)
            ((float*)&sW4[kown])[ch] = rr36;   // per-ch component: no race
    } else {
        // wave 3: build the knot float4 table for the apply phase
        if (lane < NK)
            sX[lane] = make_float4(sxs[lane*3+0], sxs[lane*3+1], sxs[lane*3+2], 0.f);
    }
    __syncthreads();

    // ================= Phase 2: apply (unchanged math) =================
    int p8 = blockIdx.x * 256 + tid;          // 8-pixel group within batch
    if (p8 * PX >= HW) return;

    size_t off = (size_t)b * HW * 3 + (size_t)p8 * (PX * 3);
    const float4* src = (const float4*)(raw + off);
    float f[PX * 3];
    #pragma unroll
    for (int j = 0; j < PX * 3 / 4; ++j) {
        float4 v = src[j];
        f[j*4+0] = v.x; f[j*4+1] = v.y; f[j*4+2] = v.z; f[j*4+3] = v.w;
    }

    float4 wb  = sW4[NK];                                      // bias row
    float4 w33 = sW4[NK+1], w34 = sW4[NK+2], w35 = sW4[NK+3];  // linear rows
    float acc[PX * 3];
    #pragma unroll
    for (int p = 0; p < PX; ++p) {
        float c0 = f[p*3+0], c1 = f[p*3+1], c2 = f[p*3+2];
        acc[p*3+0] = wb.x + c0*w33.x + c1*w34.x + c2*w35.x;
        acc[p*3+1] = wb.y + c0*w33.y + c1*w34.y + c2*w35.y;
        acc[p*3+2] = wb.z + c0*w33.z + c1*w34.z + c2*w35.z;
    }

    #pragma unroll 4
    for (int k = 0; k < NK; ++k) {
        float4 x = sX[k];
        float4 w = sW4[k];
        #pragma unroll
        for (int p = 0; p < PX; ++p) {
            float dx = f[p*3+0] - x.x;
            float dy = f[p*3+1] - x.y;
            float dz = f[p*3+2] - x.z;
            float d  = hw_sqrtf(dx*dx + dy*dy + dz*dz);
            acc[p*3+0] += d * w.x;
            acc[p*3+1] += d * w.y;
            acc[p*3+2] += d * w.z;
        }
    }

    float4* dst = (float4*)(out + off);
    #pragma unroll
    for (int j = 0; j < PX * 3 / 4; ++j)
        dst[j] = make_float4(acc[j*4+0], acc[j*4+1], acc[j*4+2], acc[j*4+3]);
}

extern "C" void kernel_launch(void* const* d_in, const int* in_sizes, int n_in,
                              void* d_out, int out_size, void* d_ws, size_t ws_size,
                              hipStream_t stream) {
    const float* raw    = (const float*)d_in[0];
    const float* params = (const float*)d_in[1];
    float* out = (float*)d_out;

    int B  = in_sizes[1] / (6 * NK + 3);
    int HW = in_sizes[0] / (B * 3);

    int groups = HW / PX;                      // HW = 200704 -> 25088, exact
    int bpb = (groups + 255) / 256;            // 98 blocks per batch
    tps_fused<<<dim3(bpb, B), dim3(256), 0, stream>>>(raw, params, out, HW);
}